// Round 6
// baseline (291.949 us; speedup 1.0000x reference)
//
#include <hip/hip_runtime.h>

typedef unsigned int u32;
typedef int i32x4 __attribute__((ext_vector_type(4)));
typedef int i32x16 __attribute__((ext_vector_type(16)));

// ws layout (bytes):
//   [0..3]      amax (float)
//   [64..1087]  256 partial maxima (float)
//   [2048..]    Wq: [1024 n][768 k] signed int8 (same layout as W_in)
#define WQ_OFF 2048

__device__ __forceinline__ void gld16(const void* g, void* l) {
    __builtin_amdgcn_global_load_lds(
        (const __attribute__((address_space(1))) void*)g,
        (__attribute__((address_space(3))) void*)l, 16, 0, 0);
}

// ---------------------------------------------------------------------------
// absmax two-stage tree (no atomics)
// ---------------------------------------------------------------------------
__global__ __launch_bounds__(256) void amax_stage1(const float* __restrict__ W,
                                                   float* __restrict__ part) {
    int t = blockIdx.x * 256 + threadIdx.x;
    float v = 0.0f;
#pragma unroll
    for (int k = 0; k < 12; ++k) v = fmaxf(v, fabsf(W[t + (k << 16)]));
#pragma unroll
    for (int d = 32; d >= 1; d >>= 1) v = fmaxf(v, __shfl_xor(v, d));
    __shared__ float sm[4];
    if ((threadIdx.x & 63) == 0) sm[threadIdx.x >> 6] = v;
    __syncthreads();
    if (threadIdx.x == 0)
        part[blockIdx.x] = fmaxf(fmaxf(sm[0], sm[1]), fmaxf(sm[2], sm[3]));
}

__global__ __launch_bounds__(256) void amax_stage2(const float* __restrict__ part,
                                                   float* __restrict__ amax) {
    float v = part[threadIdx.x];
#pragma unroll
    for (int d = 32; d >= 1; d >>= 1) v = fmaxf(v, __shfl_xor(v, d));
    __shared__ float sm[4];
    if ((threadIdx.x & 63) == 0) sm[threadIdx.x >> 6] = v;
    __syncthreads();
    if (threadIdx.x == 0)
        amax[0] = fmaxf(fmaxf(sm[0], sm[1]), fmaxf(sm[2], sm[3]));
}

// ---------------------------------------------------------------------------
// quantize W_in -> signed i8, same [1024][768] layout
// ---------------------------------------------------------------------------
__global__ __launch_bounds__(256) void quant_k(const float* __restrict__ W,
                                               const float* __restrict__ amax,
                                               u32* __restrict__ Wq4) {
    int i = blockIdx.x * 256 + threadIdx.x;     // dword index, 196608 total
    float s = 127.0f / amax[0];
    float4 v = ((const float4*)W)[i];
    int a0 = (int)rintf(v.x * s), a1 = (int)rintf(v.y * s);
    int a2 = (int)rintf(v.z * s), a3 = (int)rintf(v.w * s);
    Wq4[i] = (u32)(a0 & 0xFF) | ((u32)(a1 & 0xFF) << 8) |
             ((u32)(a2 & 0xFF) << 16) | ((u32)(a3 & 0xFF) << 24);
}

// ---------------------------------------------------------------------------
// Fused forward. 128 rows/block, 512 blocks -> 2 blocks/CU (TLP covers
// barrier drains and A-phase latency). 8 waves = 4 row-strips x 2 col-halves,
// mfma_i32_32x32x32_i8, A in 96 VGPRs/lane, B chunk (64 cols x K768) in LDS.
// Chunk schedule: MFMA -> barrier -> STAGE(c+1) -> epilogue -> barrier, so
// the stage latency hides under the epilogue's W_h loads + VALU.
// ---------------------------------------------------------------------------
__global__ __launch_bounds__(512, 4) void nnue_fwd(
    const float* __restrict__ x,       // [B][768], values in {0,1}
    const signed char* __restrict__ Wq,// [1024][768] i8
    const float* __restrict__ amax,
    const float* __restrict__ b_in,    // [1024]
    const float* __restrict__ W_h,     // [8][1024]
    const float* __restrict__ b_h,     // [8]
    const float* __restrict__ W_psqt,  // [768]
    float* __restrict__ out) {         // [B]

    __shared__ __align__(16) signed char bs8[48 * 1024];   // [kc][col][16B]
    __shared__ int   bmeta[128];
    __shared__ float pmeta[128];
    __shared__ float comb[128][2];

    const int t = threadIdx.x;
    const int l = t & 63, w = t >> 6;
    const int cl = l & 31;              // row-in-strip (A) / col-in-tile (B)
    const int hi = l >> 5;              // K-half selector
    const int strip = w >> 1, hf = w & 1;
    const size_t row0 = (size_t)blockIdx.x << 7;
    const int r = (strip << 5) + cl;    // this lane's A row (0..127)

    // ---- stage B chunk 0 early (latency hides under the A phase) --------
#define STAGE(c)                                                            \
    _Pragma("unroll")                                                       \
    for (int i = 0; i < 6; ++i)                                             \
        gld16(Wq + (size_t)(((c) << 6) + l) * 768 + (((i << 3) + w) << 4),  \
              &bs8[(i << 13) + (w << 10)]);
    STAGE(0)

    // ---- A: load x in fragment order, pack to i8, popcount + psqt -------
    i32x4 A[24];
    u32 csum = 0;
    float ps = 0.0f;
    {
        const float4* xr = (const float4*)(x + (row0 + r) * 768);
        const float4* pw = (const float4*)W_psqt;
#define PKB(f) ((__float_as_uint(f.x) >> 29)         |                      \
                ((__float_as_uint(f.y) >> 29) << 8)  |                      \
                ((__float_as_uint(f.z) >> 29) << 16) |                      \
                ((__float_as_uint(f.w) >> 29) << 24))
#define DOT4(f, q) ps = fmaf(f.x, q.x, ps); ps = fmaf(f.y, q.y, ps);        \
                   ps = fmaf(f.z, q.z, ps); ps = fmaf(f.w, q.w, ps);
#pragma unroll
        for (int ks = 0; ks < 24; ++ks) {
            int q4 = (ks << 3) + (hi << 2);     // k = ks*32 + hi*16
            float4 f0 = xr[q4 + 0], f1 = xr[q4 + 1];
            float4 f2 = xr[q4 + 2], f3 = xr[q4 + 3];
            float4 p0 = pw[q4 + 0], p1 = pw[q4 + 1];
            float4 p2 = pw[q4 + 2], p3 = pw[q4 + 3];
            u32 d0 = PKB(f0), d1 = PKB(f1), d2 = PKB(f2), d3 = PKB(f3);
            csum += d0 + d1 + d2 + d3;          // byte-lane sums <= 96
            DOT4(f0, p0) DOT4(f1, p1) DOT4(f2, p2) DOT4(f3, p3)
            A[ks] = (i32x4){(int)d0, (int)d1, (int)d2, (int)d3};
        }
#undef DOT4
#undef PKB
    }
    int cnt = (csum & 0xFF) + ((csum >> 8) & 0xFF) +
              ((csum >> 16) & 0xFF) + (csum >> 24);
    cnt += __shfl_xor(cnt, 32);                 // pair (l, l^32) = full row
    ps  += __shfl_xor(ps, 32);
    if (hi == 0) {                              // intra-wave meta (own strip)
        bmeta[r] = (cnt - 1) >> 2;
        pmeta[r] = ps;
    }

    // per-lane epilogue row table: row_in_strip = (g&3) + 8*(g>>2) + 4*hi
    int whoff[16];
#pragma unroll
    for (int g = 0; g < 16; ++g) {
        int er = (strip << 5) + (g & 3) + ((g >> 2) << 3) + (hi << 2);
        whoff[g] = bmeta[er] << 10;             // bucket*1024
    }

    const float sc = amax[0] * (1.0f / 127.0f);
    float rs[16];
#pragma unroll
    for (int g = 0; g < 16; ++g) rs[g] = 0.0f;

    __syncthreads();        // drains vmcnt(0): B chunk 0 ready; meta visible

    // ---- main loop: 16 chunks of 64 cols (this wave: 32 of them) --------
    for (int c = 0; c < 16; ++c) {
        i32x16 acc = {0,0,0,0,0,0,0,0,0,0,0,0,0,0,0,0};
#pragma unroll
        for (int ks = 0; ks < 24; ++ks) {
            const int kc = (ks << 1) + hi;
            const signed char* bp = &bs8[(kc << 10) + (((hf << 5) + cl) << 4)];
            acc = __builtin_amdgcn_mfma_i32_32x32x32_i8(
                      A[ks], *(const i32x4*)bp, acc, 0, 0, 0);
        }

        __syncthreads();                // all waves done reading bs8[c]
        if (c < 15) STAGE(c + 1)        // issue async stage; hides under epi

        // fused epilogue for this chunk (acc -> h -> bucket-head dot)
        const int col0 = (c << 6) + (hf << 5) + cl;
        const float bi = b_in[col0];
#pragma unroll
        for (int g = 0; g < 16; ++g) {
            float h = fminf(fmaxf(fmaf((float)acc[g], sc, bi), 0.f), 1.f);
            rs[g] = fmaf(h, W_h[whoff[g] + col0], rs[g]);
        }

        if (c < 15) __syncthreads();    // vmcnt(0) drain: next chunk ready
    }
#undef STAGE

    // ---- reduce over 32 col-lanes, combine col-halves, write ------------
#pragma unroll
    for (int g = 0; g < 16; ++g) {
#pragma unroll
        for (int d = 1; d < 32; d <<= 1) rs[g] += __shfl_xor(rs[g], d);
    }
    if (cl == 0) {
#pragma unroll
        for (int g = 0; g < 16; ++g) {
            int er = (strip << 5) + (g & 3) + ((g >> 2) << 3) + (hi << 2);
            comb[er][hf] = rs[g];
        }
    }
    __syncthreads();
    if (t < 128) {
        out[row0 + t] = comb[t][0] + comb[t][1] + pmeta[t] + b_h[bmeta[t]];
    }
}

extern "C" void kernel_launch(void* const* d_in, const int* in_sizes, int n_in,
                              void* d_out, int out_size, void* d_ws, size_t ws_size,
                              hipStream_t stream) {
    const float* x      = (const float*)d_in[0];
    const float* W_in   = (const float*)d_in[1];
    const float* b_in   = (const float*)d_in[2];
    const float* W_h    = (const float*)d_in[3];
    const float* b_h    = (const float*)d_in[4];
    const float* W_psqt = (const float*)d_in[5];
    float* out = (float*)d_out;

    float* amax = (float*)d_ws;
    float* part = (float*)((char*)d_ws + 64);
    signed char* Wq = (signed char*)d_ws + WQ_OFF;      // 768 KB

    amax_stage1<<<256, 256, 0, stream>>>(W_in, part);
    amax_stage2<<<1, 256, 0, stream>>>(part, amax);
    quant_k<<<768, 256, 0, stream>>>(W_in, amax, (u32*)Wq);

    int B = out_size;                   // 65536
    nnue_fwd<<<B / 128, 512, 0, stream>>>(x, Wq, amax, b_in, W_h, b_h,
                                          W_psqt, out);
}

// Round 7
// 155.784 us; speedup vs baseline: 1.8741x; 1.8741x over previous
//
#include <hip/hip_runtime.h>

typedef unsigned int u32;
typedef int i32x4 __attribute__((ext_vector_type(4)));
typedef int i32x16 __attribute__((ext_vector_type(16)));

// ws layout (bytes):
//   [0..3]      amax (float)
//   [64..1087]  256 partial maxima (float)
//   [2048..]    Wq: [1024 n][768 k] signed int8 (same layout as W_in)
#define WQ_OFF 2048

__device__ __forceinline__ void gld16(const void* g, void* l) {
    __builtin_amdgcn_global_load_lds(
        (const __attribute__((address_space(1))) void*)g,
        (__attribute__((address_space(3))) void*)l, 16, 0, 0);
}

// ---------------------------------------------------------------------------
// absmax two-stage tree (no atomics)
// ---------------------------------------------------------------------------
__global__ __launch_bounds__(256) void amax_stage1(const float* __restrict__ W,
                                                   float* __restrict__ part) {
    int t = blockIdx.x * 256 + threadIdx.x;
    float v = 0.0f;
#pragma unroll
    for (int k = 0; k < 12; ++k) v = fmaxf(v, fabsf(W[t + (k << 16)]));
#pragma unroll
    for (int d = 32; d >= 1; d >>= 1) v = fmaxf(v, __shfl_xor(v, d));
    __shared__ float sm[4];
    if ((threadIdx.x & 63) == 0) sm[threadIdx.x >> 6] = v;
    __syncthreads();
    if (threadIdx.x == 0)
        part[blockIdx.x] = fmaxf(fmaxf(sm[0], sm[1]), fmaxf(sm[2], sm[3]));
}

__global__ __launch_bounds__(256) void amax_stage2(const float* __restrict__ part,
                                                   float* __restrict__ amax) {
    float v = part[threadIdx.x];
#pragma unroll
    for (int d = 32; d >= 1; d >>= 1) v = fmaxf(v, __shfl_xor(v, d));
    __shared__ float sm[4];
    if ((threadIdx.x & 63) == 0) sm[threadIdx.x >> 6] = v;
    __syncthreads();
    if (threadIdx.x == 0)
        amax[0] = fmaxf(fmaxf(sm[0], sm[1]), fmaxf(sm[2], sm[3]));
}

// ---------------------------------------------------------------------------
// quantize W_in -> signed i8, same [1024][768] layout
// ---------------------------------------------------------------------------
__global__ __launch_bounds__(256) void quant_k(const float* __restrict__ W,
                                               const float* __restrict__ amax,
                                               u32* __restrict__ Wq4) {
    int i = blockIdx.x * 256 + threadIdx.x;     // dword index, 196608 total
    float s = 127.0f / amax[0];
    float4 v = ((const float4*)W)[i];
    int a0 = (int)rintf(v.x * s), a1 = (int)rintf(v.y * s);
    int a2 = (int)rintf(v.z * s), a3 = (int)rintf(v.w * s);
    Wq4[i] = (u32)(a0 & 0xFF) | ((u32)(a1 & 0xFF) << 8) |
             ((u32)(a2 & 0xFF) << 16) | ((u32)(a3 & 0xFF) << 24);
}

// ---------------------------------------------------------------------------
// Fused forward. 128 rows/block, 512 blocks -> 2 blocks/CU.
// 8 waves = 4 row-strips x 2 col-halves, mfma_i32_32x32x32_i8.
// A (binary x) held as a 384-BIT mask = 12 VGPRs/lane; expanded to i8
// fragments inside the chunk loop (anti-hoist asm keeps it there).
// B chunk (64 cols x K=768) staged in LDS [48 kc][64 col][16B] = 48 KB.
// Chunk schedule: MFMA -> barrier -> STAGE(c+1) -> epilogue -> barrier.
// ---------------------------------------------------------------------------
__global__ __launch_bounds__(512, 4) void nnue_fwd(
    const float* __restrict__ x,       // [B][768], values in {0,1}
    const signed char* __restrict__ Wq,// [1024][768] i8
    const float* __restrict__ amax,
    const float* __restrict__ b_in,    // [1024]
    const float* __restrict__ W_h,     // [8][1024]
    const float* __restrict__ b_h,     // [8]
    const float* __restrict__ W_psqt,  // [768]
    float* __restrict__ out) {         // [B]

    __shared__ __align__(16) signed char bs8[48 * 1024];   // [kc][col][16B]
    __shared__ int   bmeta[128];
    __shared__ float pmeta[128];
    __shared__ float comb[128][2];

    const int t = threadIdx.x;
    const int l = t & 63, w = t >> 6;
    const int cl = l & 31;              // row-in-strip (A) / col-in-tile (B)
    const int hi = l >> 5;              // K-half selector
    const int strip = w >> 1, hf = w & 1;
    const size_t row0 = (size_t)blockIdx.x << 7;
    const int r = (strip << 5) + cl;    // this lane's A row (0..127)

    // ---- stage B chunk 0 early (latency hides under the A phase) --------
#define STAGE(c)                                                            \
    _Pragma("unroll")                                                       \
    for (int i = 0; i < 6; ++i)                                             \
        gld16(Wq + (size_t)(((c) << 6) + l) * 768 + (((i << 3) + w) << 4),  \
              &bs8[(i << 13) + (w << 10)]);
    STAGE(0)

    // ---- A: load x, pack to BITS (12 regs), popcount + psqt -------------
    u32 Abits[12];
    u32 csum = 0;
    float ps = 0.0f;
    {
        const float4* xr = (const float4*)(x + (row0 + r) * 768);
        const float4* pw = (const float4*)W_psqt;
#define PKB(f) ((__float_as_uint(f.x) >> 29)         |                      \
                ((__float_as_uint(f.y) >> 29) << 8)  |                      \
                ((__float_as_uint(f.z) >> 29) << 16) |                      \
                ((__float_as_uint(f.w) >> 29) << 24))
#define DOT4(f, q) ps = fmaf(f.x, q.x, ps); ps = fmaf(f.y, q.y, ps);        \
                   ps = fmaf(f.z, q.z, ps); ps = fmaf(f.w, q.w, ps);
#pragma unroll
        for (int ks = 0; ks < 24; ++ks) {
            int q4 = (ks << 3) + (hi << 2);     // k = ks*32 + hi*16
            float4 f0 = xr[q4 + 0], f1 = xr[q4 + 1];
            float4 f2 = xr[q4 + 2], f3 = xr[q4 + 3];
            float4 p0 = pw[q4 + 0], p1 = pw[q4 + 1];
            float4 p2 = pw[q4 + 2], p3 = pw[q4 + 3];
            u32 d0 = PKB(f0), d1 = PKB(f1), d2 = PKB(f2), d3 = PKB(f3);
            csum += d0 + d1 + d2 + d3;          // byte-lane sums <= 96
            DOT4(f0, p0) DOT4(f1, p1) DOT4(f2, p2) DOT4(f3, p3)
            // compress 16 offset-bytes (0/1) -> 16 bits, elem j -> bit j
            u32 m16 = ((d0 * 0x01020408u) >> 24)
                    | (((d1 * 0x01020408u) >> 24) << 4)
                    | (((d2 * 0x01020408u) >> 24) << 8)
                    | (((d3 * 0x01020408u) >> 24) << 12);
            Abits[ks >> 1] = (ks & 1) ? (Abits[ks >> 1] | (m16 << 16)) : m16;
        }
#undef DOT4
#undef PKB
    }
    int cnt = (csum & 0xFF) + ((csum >> 8) & 0xFF) +
              ((csum >> 16) & 0xFF) + (csum >> 24);
    cnt += __shfl_xor(cnt, 32);                 // pair (l, l^32) = full row
    ps  += __shfl_xor(ps, 32);
    if (hi == 0) {                              // intra-wave meta (own strip)
        bmeta[r] = (cnt - 1) >> 2;
        pmeta[r] = ps;
    }

    // per-lane epilogue row table: row_in_strip = (g&3) + 8*(g>>2) + 4*hi
    int whoff[16];
#pragma unroll
    for (int g = 0; g < 16; ++g) {
        int er = (strip << 5) + (g & 3) + ((g >> 2) << 3) + (hi << 2);
        whoff[g] = bmeta[er] << 10;             // bucket*1024
    }

    const float sc = amax[0] * (1.0f / 127.0f);
    float rs[16];
#pragma unroll
    for (int g = 0; g < 16; ++g) rs[g] = 0.0f;

    __syncthreads();        // drains vmcnt(0): B chunk 0 ready; meta visible

    // ---- main loop: 16 chunks of 64 cols --------------------------------
    for (int c = 0; c < 16; ++c) {
        i32x16 acc = {0,0,0,0,0,0,0,0,0,0,0,0,0,0,0,0};
#pragma unroll
        for (int ks = 0; ks < 24; ++ks) {
            u32 pair = Abits[ks >> 1];
            asm volatile("" : "+v"(pair));      // defeat cross-chunk hoist
            u32 m = (ks & 1) ? (pair >> 16) : (pair & 0xFFFFu);
            // expand 16 bits -> 16 i8 (bit j -> byte j of the fragment)
            i32x4 af;
            af[0] = (int)(((m         & 0xFu) * 0x00204081u) & 0x01010101u);
            af[1] = (int)((((m >> 4)  & 0xFu) * 0x00204081u) & 0x01010101u);
            af[2] = (int)((((m >> 8)  & 0xFu) * 0x00204081u) & 0x01010101u);
            af[3] = (int)((((m >> 12)       ) * 0x00204081u) & 0x01010101u);
            const int kc = (ks << 1) + hi;
            const signed char* bp = &bs8[(kc << 10) + (((hf << 5) + cl) << 4)];
            acc = __builtin_amdgcn_mfma_i32_32x32x32_i8(
                      af, *(const i32x4*)bp, acc, 0, 0, 0);
        }

        __syncthreads();                // all waves done reading bs8[c]
        if (c < 15) STAGE(c + 1)        // async stage; hides under epilogue

        // fused epilogue for this chunk (acc -> h -> bucket-head dot)
        const int col0 = (c << 6) + (hf << 5) + cl;
        const float bi = b_in[col0];
#pragma unroll
        for (int g = 0; g < 16; ++g) {
            float h = fminf(fmaxf(fmaf((float)acc[g], sc, bi), 0.f), 1.f);
            rs[g] = fmaf(h, W_h[whoff[g] + col0], rs[g]);
        }

        if (c < 15) __syncthreads();    // vmcnt(0) drain: next chunk ready
    }
#undef STAGE

    // ---- reduce over 32 col-lanes, combine col-halves, write ------------
#pragma unroll
    for (int g = 0; g < 16; ++g) {
#pragma unroll
        for (int d = 1; d < 32; d <<= 1) rs[g] += __shfl_xor(rs[g], d);
    }
    if (cl == 0) {
#pragma unroll
        for (int g = 0; g < 16; ++g) {
            int er = (strip << 5) + (g & 3) + ((g >> 2) << 3) + (hi << 2);
            comb[er][hf] = rs[g];
        }
    }
    __syncthreads();
    if (t < 128) {
        out[row0 + t] = comb[t][0] + comb[t][1] + pmeta[t] + b_h[bmeta[t]];
    }
}

extern "C" void kernel_launch(void* const* d_in, const int* in_sizes, int n_in,
                              void* d_out, int out_size, void* d_ws, size_t ws_size,
                              hipStream_t stream) {
    const float* x      = (const float*)d_in[0];
    const float* W_in   = (const float*)d_in[1];
    const float* b_in   = (const float*)d_in[2];
    const float* W_h    = (const float*)d_in[3];
    const float* b_h    = (const float*)d_in[4];
    const float* W_psqt = (const float*)d_in[5];
    float* out = (float*)d_out;

    float* amax = (float*)d_ws;
    float* part = (float*)((char*)d_ws + 64);
    signed char* Wq = (signed char*)d_ws + WQ_OFF;      // 768 KB

    amax_stage1<<<256, 256, 0, stream>>>(W_in, part);
    amax_stage2<<<1, 256, 0, stream>>>(part, amax);
    quant_k<<<768, 256, 0, stream>>>(W_in, amax, (u32*)Wq);

    int B = out_size;                   // 65536
    nnue_fwd<<<B / 128, 512, 0, stream>>>(x, Wq, amax, b_in, W_h, b_h,
                                          W_psqt, out);
}

// Round 8
// 113.211 us; speedup vs baseline: 2.5788x; 1.3761x over previous
//
#include <hip/hip_runtime.h>

typedef unsigned int u32;
typedef int i32x4 __attribute__((ext_vector_type(4)));
typedef int i32x16 __attribute__((ext_vector_type(16)));

// ws layout (bytes):
//   [0..3]      amax (float)
//   [64..1087]  256 partial maxima (float)
//   [2048..]    Wq: [1024 n][768 k] signed int8 (same layout as W_in)
#define WQ_OFF 2048

__device__ __forceinline__ void gld16(const void* g, void* l) {
    __builtin_amdgcn_global_load_lds(
        (const __attribute__((address_space(1))) void*)g,
        (__attribute__((address_space(3))) void*)l, 16, 0, 0);
}

// ---------------------------------------------------------------------------
// absmax two-stage tree (no atomics)
// ---------------------------------------------------------------------------
__global__ __launch_bounds__(256) void amax_stage1(const float* __restrict__ W,
                                                   float* __restrict__ part) {
    int t = blockIdx.x * 256 + threadIdx.x;
    float v = 0.0f;
#pragma unroll
    for (int k = 0; k < 12; ++k) v = fmaxf(v, fabsf(W[t + (k << 16)]));
#pragma unroll
    for (int d = 32; d >= 1; d >>= 1) v = fmaxf(v, __shfl_xor(v, d));
    __shared__ float sm[4];
    if ((threadIdx.x & 63) == 0) sm[threadIdx.x >> 6] = v;
    __syncthreads();
    if (threadIdx.x == 0)
        part[blockIdx.x] = fmaxf(fmaxf(sm[0], sm[1]), fmaxf(sm[2], sm[3]));
}

__global__ __launch_bounds__(256) void amax_stage2(const float* __restrict__ part,
                                                   float* __restrict__ amax) {
    float v = part[threadIdx.x];
#pragma unroll
    for (int d = 32; d >= 1; d >>= 1) v = fmaxf(v, __shfl_xor(v, d));
    __shared__ float sm[4];
    if ((threadIdx.x & 63) == 0) sm[threadIdx.x >> 6] = v;
    __syncthreads();
    if (threadIdx.x == 0)
        amax[0] = fmaxf(fmaxf(sm[0], sm[1]), fmaxf(sm[2], sm[3]));
}

// ---------------------------------------------------------------------------
// quantize W_in -> signed i8, same [1024][768] layout
// ---------------------------------------------------------------------------
__global__ __launch_bounds__(256) void quant_k(const float* __restrict__ W,
                                               const float* __restrict__ amax,
                                               u32* __restrict__ Wq4) {
    int i = blockIdx.x * 256 + threadIdx.x;     // dword index, 196608 total
    float s = 127.0f / amax[0];
    float4 v = ((const float4*)W)[i];
    int a0 = (int)rintf(v.x * s), a1 = (int)rintf(v.y * s);
    int a2 = (int)rintf(v.z * s), a3 = (int)rintf(v.w * s);
    Wq4[i] = (u32)(a0 & 0xFF) | ((u32)(a1 & 0xFF) << 8) |
             ((u32)(a2 & 0xFF) << 16) | ((u32)(a3 & 0xFF) << 24);
}

// ---------------------------------------------------------------------------
// Fused forward. 128 rows/block, 512 blocks -> 2 blocks/CU.
// 256 threads = 4 waves; each wave owns one 32-row strip and BOTH 32-col
// tiles of the 64-col chunk (A-fragment expanded once, used by 2 MFMAs).
// A (binary x) held as 384-bit mask = 12 VGPRs/lane; expanded in-loop.
// B chunk (64 cols x K=768) staged in LDS [48 kc][64 col][16B] = 48 KB.
// launch_bounds(256,4): 128-VGPR cap under either min-waves/EU or
// min-blocks/CU semantics -> no spill (live set ~95).
// ---------------------------------------------------------------------------
__global__ __launch_bounds__(256, 4) void nnue_fwd(
    const float* __restrict__ x,       // [B][768], values in {0,1}
    const signed char* __restrict__ Wq,// [1024][768] i8
    const float* __restrict__ amax,
    const float* __restrict__ b_in,    // [1024]
    const float* __restrict__ W_h,     // [8][1024]
    const float* __restrict__ b_h,     // [8]
    const float* __restrict__ W_psqt,  // [768]
    float* __restrict__ out) {         // [B]

    __shared__ __align__(16) signed char bs8[48 * 1024];   // [kc][col][16B]
    __shared__ int   bmeta[128];
    __shared__ float pmeta[128];

    const int t = threadIdx.x;
    const int l = t & 63, w = t >> 6;   // 4 waves
    const int cl = l & 31;              // row-in-strip (A) / col-in-tile (B)
    const int hi = l >> 5;              // K-half selector
    const size_t row0 = (size_t)blockIdx.x << 7;
    const int r = (w << 5) + cl;        // this lane's A row (0..127)

    // ---- stage B chunk 0 early (latency hides under the A phase) --------
#define STAGE(c)                                                            \
    _Pragma("unroll")                                                       \
    for (int i = 0; i < 12; ++i)                                            \
        gld16(Wq + (size_t)(((c) << 6) + l) * 768 + (((i << 2) + w) << 4),  \
              &bs8[(i << 12) + (w << 10)]);
    STAGE(0)

    // ---- A: load x, pack to BITS (12 regs), popcount + psqt -------------
    u32 Abits[12];
    u32 csum = 0;
    float ps = 0.0f;
    {
        const float4* xr = (const float4*)(x + (row0 + r) * 768);
        const float4* pw = (const float4*)W_psqt;
#define PKB(f) ((__float_as_uint(f.x) >> 29)         |                      \
                ((__float_as_uint(f.y) >> 29) << 8)  |                      \
                ((__float_as_uint(f.z) >> 29) << 16) |                      \
                ((__float_as_uint(f.w) >> 29) << 24))
#define DOT4(f, q) ps = fmaf(f.x, q.x, ps); ps = fmaf(f.y, q.y, ps);        \
                   ps = fmaf(f.z, q.z, ps); ps = fmaf(f.w, q.w, ps);
#pragma unroll
        for (int ks = 0; ks < 24; ++ks) {
            int q4 = (ks << 3) + (hi << 2);     // k = ks*32 + hi*16
            float4 f0 = xr[q4 + 0], f1 = xr[q4 + 1];
            float4 f2 = xr[q4 + 2], f3 = xr[q4 + 3];
            float4 p0 = pw[q4 + 0], p1 = pw[q4 + 1];
            float4 p2 = pw[q4 + 2], p3 = pw[q4 + 3];
            u32 d0 = PKB(f0), d1 = PKB(f1), d2 = PKB(f2), d3 = PKB(f3);
            csum += d0 + d1 + d2 + d3;          // byte-lane sums <= 96
            DOT4(f0, p0) DOT4(f1, p1) DOT4(f2, p2) DOT4(f3, p3)
            // compress 16 offset-bytes (0/1) -> 16 bits, elem j -> bit j
            u32 m16 = ((d0 * 0x01020408u) >> 24)
                    | (((d1 * 0x01020408u) >> 24) << 4)
                    | (((d2 * 0x01020408u) >> 24) << 8)
                    | (((d3 * 0x01020408u) >> 24) << 12);
            Abits[ks >> 1] = (ks & 1) ? (Abits[ks >> 1] | (m16 << 16)) : m16;
        }
#undef DOT4
#undef PKB
    }
    int cnt = (csum & 0xFF) + ((csum >> 8) & 0xFF) +
              ((csum >> 16) & 0xFF) + (csum >> 24);
    cnt += __shfl_xor(cnt, 32);                 // pair (l, l^32) = full row
    ps  += __shfl_xor(ps, 32);
    if (hi == 0) {                              // intra-wave meta (own strip)
        bmeta[r] = (cnt - 1) >> 2;
        pmeta[r] = ps;
    }

    const float sc = amax[0] * (1.0f / 127.0f);
    float rs[16];
#pragma unroll
    for (int g = 0; g < 16; ++g) rs[g] = 0.0f;

    __syncthreads();        // drains vmcnt(0): B chunk 0 ready; meta visible

    // per-lane epilogue row table: row_in_strip = (g&3) + 8*(g>>2) + 4*hi
    int whoff[16];
#pragma unroll
    for (int g = 0; g < 16; ++g) {
        int er = (w << 5) + (g & 3) + ((g >> 2) << 3) + (hi << 2);
        whoff[g] = bmeta[er] << 10;             // bucket*1024
    }

    // ---- main loop: 16 chunks of 64 cols (2 col-tiles per wave) ---------
    for (int c = 0; c < 16; ++c) {
        i32x16 acc0 = {0,0,0,0,0,0,0,0,0,0,0,0,0,0,0,0};
        i32x16 acc1 = {0,0,0,0,0,0,0,0,0,0,0,0,0,0,0,0};
#pragma unroll
        for (int ks = 0; ks < 24; ++ks) {
            u32 pair = Abits[ks >> 1];
            asm volatile("" : "+v"(pair));      // defeat cross-chunk hoist
            u32 m = (ks & 1) ? (pair >> 16) : (pair & 0xFFFFu);
            // expand 16 bits -> 16 i8 (bit j -> byte j of the fragment)
            i32x4 af;
            af[0] = (int)(((m         & 0xFu) * 0x00204081u) & 0x01010101u);
            af[1] = (int)((((m >> 4)  & 0xFu) * 0x00204081u) & 0x01010101u);
            af[2] = (int)((((m >> 8)  & 0xFu) * 0x00204081u) & 0x01010101u);
            af[3] = (int)((((m >> 12)       ) * 0x00204081u) & 0x01010101u);
            const int kc = (ks << 1) + hi;
            const signed char* bp = &bs8[(kc << 10) + (cl << 4)];
            acc0 = __builtin_amdgcn_mfma_i32_32x32x32_i8(
                       af, *(const i32x4*)bp, acc0, 0, 0, 0);
            acc1 = __builtin_amdgcn_mfma_i32_32x32x32_i8(
                       af, *(const i32x4*)(bp + 512), acc1, 0, 0, 0);
        }

        __syncthreads();                // all waves done reading bs8[c]
        if (c < 15) STAGE(c + 1)        // async stage; hides under epilogue

        // fused epilogue: both col-tiles -> same per-row dot rs[g]
        const int col0 = (c << 6) + cl;
        const float bi0 = b_in[col0], bi1 = b_in[col0 + 32];
#pragma unroll
        for (int g = 0; g < 16; ++g) {
            float h0 = fminf(fmaxf(fmaf((float)acc0[g], sc, bi0), 0.f), 1.f);
            float h1 = fminf(fmaxf(fmaf((float)acc1[g], sc, bi1), 0.f), 1.f);
            rs[g] = fmaf(h0, W_h[whoff[g] + col0], rs[g]);
            rs[g] = fmaf(h1, W_h[whoff[g] + col0 + 32], rs[g]);
        }

        if (c < 15) __syncthreads();    // vmcnt(0) drain: next chunk ready
    }
#undef STAGE

    // ---- reduce over 32 col-lanes (within each hi half), write ----------
#pragma unroll
    for (int g = 0; g < 16; ++g) {
#pragma unroll
        for (int d = 1; d < 32; d <<= 1) rs[g] += __shfl_xor(rs[g], d);
    }
    if (cl == 0) {
#pragma unroll
        for (int g = 0; g < 16; ++g) {
            int er = (w << 5) + (g & 3) + ((g >> 2) << 3) + (hi << 2);
            out[row0 + er] = rs[g] + pmeta[er] + b_h[whoff[g] >> 10];
        }
    }
}

extern "C" void kernel_launch(void* const* d_in, const int* in_sizes, int n_in,
                              void* d_out, int out_size, void* d_ws, size_t ws_size,
                              hipStream_t stream) {
    const float* x      = (const float*)d_in[0];
    const float* W_in   = (const float*)d_in[1];
    const float* b_in   = (const float*)d_in[2];
    const float* W_h    = (const float*)d_in[3];
    const float* b_h    = (const float*)d_in[4];
    const float* W_psqt = (const float*)d_in[5];
    float* out = (float*)d_out;

    float* amax = (float*)d_ws;
    float* part = (float*)((char*)d_ws + 64);
    signed char* Wq = (signed char*)d_ws + WQ_OFF;      // 768 KB

    amax_stage1<<<256, 256, 0, stream>>>(W_in, part);
    amax_stage2<<<1, 256, 0, stream>>>(part, amax);
    quant_k<<<768, 256, 0, stream>>>(W_in, amax, (u32*)Wq);

    int B = out_size;                   // 65536
    nnue_fwd<<<B / 128, 256, 0, stream>>>(x, Wq, amax, b_in, W_h, b_h,
                                          W_psqt, out);
}